// Round 5
// baseline (112.864 us; speedup 1.0000x reference)
//
#include <hip/hip_runtime.h>
#include <hip/hip_bf16.h>

// Problem constants: S=128, E=16, C=256, H=1024, h=64, r=16
#define S_SEG 128
#define N_IMG 16
#define N_CH  256
#define HFULL 1024
#define HSM   64
#define MIN_PIXELS 50.0f

typedef float v4 __attribute__((ext_vector_type(4)));

// ---------------------------------------------------------------------------
// Kernel 1 (fused streaming): 9216 blocks x 256 threads, 64 KB read each.
//  - blocks [0,1024): sam channel totals (mask-independent).
//  - blocks [1024,9216): mask 16x16 pooling -> sel bits.
// Round-5 change: NO non-temporal hint on mask loads (isolating NT as the
// suspected read-BW limiter; its L3-protection rationale is obsolete).
// ---------------------------------------------------------------------------
__global__ __launch_bounds__(256) void stream_all(
    const float* __restrict__ masks,
    const float* __restrict__ sam,
    unsigned short* __restrict__ selb16,
    float* __restrict__ total)
{
    const int b = blockIdx.x;
    const int t = threadIdx.x, lane = t & 63, wave = t >> 6;

    if (b < 1024) {                          // ---- sam totals ----
        const int w = b * 4 + wave;          // (e*256+c) in [0,4096)
        const v4* p = (const v4*)sam + (size_t)w * 1024;
        float sum = 0.f;
#pragma unroll
        for (int i = 0; i < 16; ++i) {
            v4 v = p[i * 64 + lane];
            sum += (v.x + v.y) + (v.z + v.w);
        }
        sum += __shfl_xor(sum, 32); sum += __shfl_xor(sum, 16);
        sum += __shfl_xor(sum, 8);  sum += __shfl_xor(sum, 4);
        sum += __shfl_xor(sum, 2);  sum += __shfl_xor(sum, 1);
        if (lane == 0) total[w] = sum;
        return;
    }

    // ---- mask pooling ----
    const int mb = b - 1024;
    const int s  = mb >> 6;                  // segment 0..127
    const int hb = mb & 63;                  // row-block 0..63
    const v4* m4 = (const v4*)(masks + (size_t)s * HFULL * HFULL
                                     + (size_t)hb * 16 * HFULL);
    float sum = 0.f;
#pragma unroll
    for (int i = 0; i < 16; ++i) {           // thread t owns cols [4t,4t+3]
        v4 v = m4[i * 256 + t];              // plain load (NT removed)
        sum += (v.x + v.y) + (v.z + v.w);
    }
    sum += __shfl_xor(sum, 1);
    sum += __shfl_xor(sum, 2);
    const float s2 = __shfl(sum, (lane & 15) * 4);
    const unsigned long long bb = __ballot(s2 >= MIN_PIXELS);
    if (lane == 0)
        selb16[(s * 64 + hb) * 4 + wave] = (unsigned short)(bb & 0xFFFFull);
}

// ---------------------------------------------------------------------------
// Kernel 2 (finish): grid = 129 blocks x 256.
//  block s<128: thread t = channel c. den = popcount(sel[s]);
//    out[s,c] = (total[e,c] - sum_{unselected hw} emb[e,c,hw]) / den.
//    Dense fast path: block-wide ballot skips the correction scan entirely
//    when sel[s] has no zero bits (always, for this input).
//  block 128: passthrough tails.
// ---------------------------------------------------------------------------
__global__ __launch_bounds__(256) void finish(
    const float* __restrict__ sam,
    const int* __restrict__ ids,
    const int* __restrict__ rel,
    const float* __restrict__ coords,
    const unsigned int* __restrict__ selbits32,
    const float* __restrict__ total,
    float* __restrict__ out)
{
    const int s = blockIdx.x;
    const int t = threadIdx.x;

    if (s == S_SEG) {                        // tails
        for (int i = t; i < 896; i += 256) {
            if (i < 128)        out[i] = (float)ids[i];
            else if (i < 256)   out[i] = (float)rel[i - 128];
            else if (i < 384)   out[i] = 0.0f;
            else                out[32768 + i] = coords[i - 384]; // 33152+(i-384)
        }
        return;
    }

    const int e = ids[s];
    __shared__ unsigned int bits[128];
    __shared__ int den_s;
    __shared__ int miss_any_s;

    if (t == 0) { den_s = 0; miss_any_s = 0; }
    __syncthreads();
    if (t < 128) bits[t] = selbits32[s * 128 + t];
    __syncthreads();
    if (t < 128) {
        const int cnt = __popc(bits[t]);
        if (cnt) atomicAdd(&den_s, cnt);
        if (cnt != 32) miss_any_s = 1;       // any zero bit in this word
    }
    __syncthreads();

    float num = total[e * N_CH + t];         // t = channel
    if (miss_any_s) {                        // corrections (rare / none)
        for (int w = 0; w < 128; ++w) {
            unsigned int miss = ~bits[w];
            while (miss) {
                const int bit = __ffs(miss) - 1;
                miss &= miss - 1;
                const int pos = w * 32 + bit;
                num -= sam[((size_t)e * N_CH + t) * (HSM * HSM) + pos];
            }
        }
    }
    out[384 + s * N_CH + t] = num / (float)den_s;
}

extern "C" void kernel_launch(void* const* d_in, const int* in_sizes, int n_in,
                              void* d_out, int out_size, void* d_ws, size_t ws_size,
                              hipStream_t stream)
{
    const float* masks  = (const float*)d_in[0];
    const float* sam    = (const float*)d_in[1];
    const int*   ids    = (const int*)d_in[2];
    const int*   rel    = (const int*)d_in[3];
    const float* coords = (const float*)d_in[4];
    float* out = (float*)d_out;

    unsigned short* selb16 = (unsigned short*)d_ws;            // 64 KB
    float* total = (float*)((char*)d_ws + 64 * 1024);          // 16 KB

    stream_all<<<dim3(1024 + 64 * S_SEG), 256, 0, stream>>>(
        masks, sam, selb16, total);
    finish<<<dim3(S_SEG + 1), 256, 0, stream>>>(
        sam, ids, rel, coords, (const unsigned int*)d_ws, total, out);
}

// Round 6
// 99.569 us; speedup vs baseline: 1.1335x; 1.1335x over previous
//
#include <hip/hip_runtime.h>
#include <hip/hip_bf16.h>

// Problem constants: S=128, E=16, C=256, H=1024, h=64, r=16
#define S_SEG 128
#define N_IMG 16
#define N_CH  256
#define HFULL 1024
#define HSM   64
#define MIN_PIXELS 50.0f

typedef float v4 __attribute__((ext_vector_type(4)));

// ---------------------------------------------------------------------------
// Kernel 1 (fused streaming, sam-LAST): 9216 blocks x 256 threads.
//  - blocks [0,8192): mask 16x16 pooling -> sel bits. NT loads (read-once,
//    keep L3 for sam across graph replays).
//  - blocks [8192,9216): sam channel totals (plain loads -> L3-resident;
//    execute during the mask-tail drain, overlap for free).
// ---------------------------------------------------------------------------
__global__ __launch_bounds__(256) void stream_all(
    const float* __restrict__ masks,
    const float* __restrict__ sam,
    unsigned short* __restrict__ selb16,
    float* __restrict__ total)
{
    const int b = blockIdx.x;
    const int t = threadIdx.x, lane = t & 63, wave = t >> 6;

    if (b >= 8192) {                         // ---- sam totals (tail) ----
        const int w = (b - 8192) * 4 + wave; // (e*256+c) in [0,4096)
        const v4* p = (const v4*)sam + (size_t)w * 1024;
        float sum = 0.f;
#pragma unroll
        for (int i = 0; i < 16; ++i) {
            v4 v = p[i * 64 + lane];
            sum += (v.x + v.y) + (v.z + v.w);
        }
        sum += __shfl_xor(sum, 32); sum += __shfl_xor(sum, 16);
        sum += __shfl_xor(sum, 8);  sum += __shfl_xor(sum, 4);
        sum += __shfl_xor(sum, 2);  sum += __shfl_xor(sum, 1);
        if (lane == 0) total[w] = sum;
        return;
    }

    // ---- mask pooling ----
    const int s  = b >> 6;                   // segment 0..127
    const int hb = b & 63;                   // row-block 0..63
    const v4* m4 = (const v4*)(masks + (size_t)s * HFULL * HFULL
                                     + (size_t)hb * 16 * HFULL);
    float sum = 0.f;
#pragma unroll
    for (int i = 0; i < 16; ++i) {           // thread t owns cols [4t,4t+3]
        v4 v = __builtin_nontemporal_load(&m4[i * 256 + t]);
        sum += (v.x + v.y) + (v.z + v.w);
    }
    sum += __shfl_xor(sum, 1);
    sum += __shfl_xor(sum, 2);
    const float s2 = __shfl(sum, (lane & 15) * 4);
    const unsigned long long bb = __ballot(s2 >= MIN_PIXELS);
    if (lane == 0)
        selb16[(s * 64 + hb) * 4 + wave] = (unsigned short)(bb & 0xFFFFull);
}

// ---------------------------------------------------------------------------
// Kernel 2 (finish): grid = 129 blocks x 256.
//  block s<128: thread t = channel c. den = popcount(sel[s]);
//    out[s,c] = (total[e,c] - sum_{unselected hw} emb[e,c,hw]) / den.
//    Dense fast path skips the correction scan when sel[s] is all-ones.
//  block 128: passthrough tails.
// ---------------------------------------------------------------------------
__global__ __launch_bounds__(256) void finish(
    const float* __restrict__ sam,
    const int* __restrict__ ids,
    const int* __restrict__ rel,
    const float* __restrict__ coords,
    const unsigned int* __restrict__ selbits32,
    const float* __restrict__ total,
    float* __restrict__ out)
{
    const int s = blockIdx.x;
    const int t = threadIdx.x;

    if (s == S_SEG) {                        // tails
        for (int i = t; i < 896; i += 256) {
            if (i < 128)        out[i] = (float)ids[i];
            else if (i < 256)   out[i] = (float)rel[i - 128];
            else if (i < 384)   out[i] = 0.0f;
            else                out[32768 + i] = coords[i - 384]; // 33152+(i-384)
        }
        return;
    }

    const int e = ids[s];
    __shared__ unsigned int bits[128];
    __shared__ int den_s;
    __shared__ int miss_any_s;

    if (t == 0) { den_s = 0; miss_any_s = 0; }
    __syncthreads();
    if (t < 128) bits[t] = selbits32[s * 128 + t];
    __syncthreads();
    if (t < 128) {
        const int cnt = __popc(bits[t]);
        if (cnt) atomicAdd(&den_s, cnt);
        if (cnt != 32) miss_any_s = 1;       // any zero bit in this word
    }
    __syncthreads();

    float num = total[e * N_CH + t];         // t = channel
    if (miss_any_s) {                        // corrections (rare / none)
        for (int w = 0; w < 128; ++w) {
            unsigned int miss = ~bits[w];
            while (miss) {
                const int bit = __ffs(miss) - 1;
                miss &= miss - 1;
                const int pos = w * 32 + bit;
                num -= sam[((size_t)e * N_CH + t) * (HSM * HSM) + pos];
            }
        }
    }
    out[384 + s * N_CH + t] = num / (float)den_s;
}

extern "C" void kernel_launch(void* const* d_in, const int* in_sizes, int n_in,
                              void* d_out, int out_size, void* d_ws, size_t ws_size,
                              hipStream_t stream)
{
    const float* masks  = (const float*)d_in[0];
    const float* sam    = (const float*)d_in[1];
    const int*   ids    = (const int*)d_in[2];
    const int*   rel    = (const int*)d_in[3];
    const float* coords = (const float*)d_in[4];
    float* out = (float*)d_out;

    unsigned short* selb16 = (unsigned short*)d_ws;            // 64 KB
    float* total = (float*)((char*)d_ws + 64 * 1024);          // 16 KB

    stream_all<<<dim3(8192 + 1024), 256, 0, stream>>>(
        masks, sam, selb16, total);
    finish<<<dim3(S_SEG + 1), 256, 0, stream>>>(
        sam, ids, rel, coords, (const unsigned int*)d_ws, total, out);
}

// Round 7
// 98.434 us; speedup vs baseline: 1.1466x; 1.0115x over previous
//
#include <hip/hip_runtime.h>
#include <hip/hip_bf16.h>

// Problem constants: S=128, E=16, C=256, H=1024, h=64, r=16
#define S_SEG 128
#define N_IMG 16
#define N_CH  256
#define HFULL 1024
#define HSM   64
#define MIN_PIXELS 50.0f

typedef float v4 __attribute__((ext_vector_type(4)));

// ---------------------------------------------------------------------------
// Kernel 1 (persistent grid-stride): exactly 2048 blocks (8/CU, 32 waves/CU).
// Each block processes 4 mask chunks (64 KB each, NT loads); blocks [0,1024)
// additionally reduce one sam chunk at the end (plain loads -> L3-resident,
// executes in the mask-drain shadow). Eliminates dispatch-generation ramp.
// ---------------------------------------------------------------------------
__global__ __launch_bounds__(256) void stream_all(
    const float* __restrict__ masks,
    const float* __restrict__ sam,
    unsigned short* __restrict__ selb16,
    float* __restrict__ total)
{
    const int b = blockIdx.x;
    const int t = threadIdx.x, lane = t & 63, wave = t >> 6;

    // ---- mask pooling: 8192 chunks, grid-stride by 2048 ----
    for (int c = b; c < 8192; c += 2048) {
        const int s  = c >> 6;               // segment 0..127
        const int hb = c & 63;               // row-block 0..63
        const v4* m4 = (const v4*)(masks + (size_t)s * HFULL * HFULL
                                         + (size_t)hb * 16 * HFULL);
        float sum = 0.f;
#pragma unroll
        for (int i = 0; i < 16; ++i) {       // thread t owns cols [4t,4t+3]
            v4 v = __builtin_nontemporal_load(&m4[i * 256 + t]);
            sum += (v.x + v.y) + (v.z + v.w);
        }
        sum += __shfl_xor(sum, 1);
        sum += __shfl_xor(sum, 2);
        const float s2 = __shfl(sum, (lane & 15) * 4);
        const unsigned long long bb = __ballot(s2 >= MIN_PIXELS);
        if (lane == 0)
            selb16[(s * 64 + hb) * 4 + wave] = (unsigned short)(bb & 0xFFFFull);
    }

    // ---- sam totals: 1024 chunks on blocks [0,1024), in the drain shadow ----
    if (b < 1024) {
        const int w = b * 4 + wave;          // (e*256+c) in [0,4096)
        const v4* p = (const v4*)sam + (size_t)w * 1024;
        float sum = 0.f;
#pragma unroll
        for (int i = 0; i < 16; ++i) {
            v4 v = p[i * 64 + lane];
            sum += (v.x + v.y) + (v.z + v.w);
        }
        sum += __shfl_xor(sum, 32); sum += __shfl_xor(sum, 16);
        sum += __shfl_xor(sum, 8);  sum += __shfl_xor(sum, 4);
        sum += __shfl_xor(sum, 2);  sum += __shfl_xor(sum, 1);
        if (lane == 0) total[w] = sum;
    }
}

// ---------------------------------------------------------------------------
// Kernel 2 (finish, UNCHANGED): grid = 129 blocks x 256.
//  block s<128: thread t = channel c. den = popcount(sel[s]);
//    out[s,c] = (total[e,c] - sum_{unselected hw} emb[e,c,hw]) / den.
//    Dense fast path skips the correction scan when sel[s] is all-ones.
//  block 128: passthrough tails.
// ---------------------------------------------------------------------------
__global__ __launch_bounds__(256) void finish(
    const float* __restrict__ sam,
    const int* __restrict__ ids,
    const int* __restrict__ rel,
    const float* __restrict__ coords,
    const unsigned int* __restrict__ selbits32,
    const float* __restrict__ total,
    float* __restrict__ out)
{
    const int s = blockIdx.x;
    const int t = threadIdx.x;

    if (s == S_SEG) {                        // tails
        for (int i = t; i < 896; i += 256) {
            if (i < 128)        out[i] = (float)ids[i];
            else if (i < 256)   out[i] = (float)rel[i - 128];
            else if (i < 384)   out[i] = 0.0f;
            else                out[32768 + i] = coords[i - 384]; // 33152+(i-384)
        }
        return;
    }

    const int e = ids[s];
    __shared__ unsigned int bits[128];
    __shared__ int den_s;
    __shared__ int miss_any_s;

    if (t == 0) { den_s = 0; miss_any_s = 0; }
    __syncthreads();
    if (t < 128) bits[t] = selbits32[s * 128 + t];
    __syncthreads();
    if (t < 128) {
        const int cnt = __popc(bits[t]);
        if (cnt) atomicAdd(&den_s, cnt);
        if (cnt != 32) miss_any_s = 1;       // any zero bit in this word
    }
    __syncthreads();

    float num = total[e * N_CH + t];         // t = channel
    if (miss_any_s) {                        // corrections (rare / none)
        for (int w = 0; w < 128; ++w) {
            unsigned int miss = ~bits[w];
            while (miss) {
                const int bit = __ffs(miss) - 1;
                miss &= miss - 1;
                const int pos = w * 32 + bit;
                num -= sam[((size_t)e * N_CH + t) * (HSM * HSM) + pos];
            }
        }
    }
    out[384 + s * N_CH + t] = num / (float)den_s;
}

extern "C" void kernel_launch(void* const* d_in, const int* in_sizes, int n_in,
                              void* d_out, int out_size, void* d_ws, size_t ws_size,
                              hipStream_t stream)
{
    const float* masks  = (const float*)d_in[0];
    const float* sam    = (const float*)d_in[1];
    const int*   ids    = (const int*)d_in[2];
    const int*   rel    = (const int*)d_in[3];
    const float* coords = (const float*)d_in[4];
    float* out = (float*)d_out;

    unsigned short* selb16 = (unsigned short*)d_ws;            // 64 KB
    float* total = (float*)((char*)d_ws + 64 * 1024);          // 16 KB

    stream_all<<<dim3(2048), 256, 0, stream>>>(masks, sam, selb16, total);
    finish<<<dim3(S_SEG + 1), 256, 0, stream>>>(
        sam, ids, rel, coords, (const unsigned int*)d_ws, total, out);
}